// Round 1
// baseline (239.742 us; speedup 1.0000x reference)
//
#include <hip/hip_runtime.h>
#include <cstdint>
#include <math.h>

#define HH 2048
#define WW 2048
#define HWPX (HH*WW)
#define NSEG 10
#define NB 256
#define LOWR 0.0625f
#define INV_LOWW 4096.0f           // NB / LOWR
#define BINW (LOWR/(float)NB)

// workspace layout (32-bit words)
#define WS_DMIN 0
#define WS_DMAX 1
#define WS_HIST 2                          // NSEG*(NB+1) uints; bin NB = overflow
#define HIST_WORDS (NSEG*(NB+1))           // 2570
#define WS_CHS (WS_HIST + HIST_WORDS)      // 2572: 30 floats (per-seg r,g,b sums)
#define WS_DSEG 2604                       // 16B-aligned: 11 float4 (seg 10 = zeros)
#define WS_TOTAL (WS_DSEG + 44)

// Segment rule: replicates bins = linspace(dmin,dmax,11); pixel in seg s iff
// bins[s] <= v < bins[s+1]. v == dmax (== bins[10]) is in NO segment -> 10.
// Interior boundary rounding vs XLA differs by <=1 pixel-segment shifts whose
// D_seg delta is ~1e-3 -> negligible. K2 and K4 use the identical rule.
__device__ __forceinline__ int seg_of(float v, float dmin, float dmax, float invw) {
    int sg = (int)((v - dmin) * invw);   // v>=dmin; INF saturates then masked below
    sg = sg > (NSEG-1) ? (NSEG-1) : sg;
    return (v >= dmax) ? NSEG : sg;
}

__global__ void k0_init(uint32_t* __restrict__ wsu) {
    int nth = gridDim.x * blockDim.x;
    int i = blockIdx.x * blockDim.x + threadIdx.x;
    for (int j = i; j < WS_TOTAL; j += nth) {
        uint32_t v = 0;
        if (j == WS_DMIN) v = 0x7F800000u;   // +inf
        // WS_DMAX init 0 (0.0f) ok: depth >= 0
        wsu[j] = v;
    }
}

__global__ __launch_bounds__(256) void k1_minmax(const float* __restrict__ depth,
                                                 uint32_t* __restrict__ wsu) {
    int tid = blockIdx.x * 256 + threadIdx.x;
    int nth = gridDim.x * 256;
    float vmin = INFINITY, vmax = 0.0f;
    const float4* d4 = (const float4*)depth;
    for (int i = tid; i < HWPX/4; i += nth) {
        float4 v = d4[i];
        vmin = fminf(vmin, fminf(fminf(v.x, v.y), fminf(v.z, v.w)));
        vmax = fmaxf(vmax, fmaxf(fmaxf(v.x, v.y), fmaxf(v.z, v.w)));
    }
    #pragma unroll
    for (int off = 32; off > 0; off >>= 1) {
        vmin = fminf(vmin, __shfl_down(vmin, off, 64));
        vmax = fmaxf(vmax, __shfl_down(vmax, off, 64));
    }
    __shared__ float smin[4], smax[4];
    int wid = threadIdx.x >> 6;
    if ((threadIdx.x & 63) == 0) { smin[wid] = vmin; smax[wid] = vmax; }
    __syncthreads();
    if (threadIdx.x == 0) {
        float bmin = fminf(fminf(smin[0], smin[1]), fminf(smin[2], smin[3]));
        float bmax = fmaxf(fmaxf(smax[0], smax[1]), fmaxf(smax[2], smax[3]));
        atomicMin(&wsu[WS_DMIN], __float_as_uint(bmin));   // depth>=0: bits ordered
        atomicMax(&wsu[WS_DMAX], __float_as_uint(bmax));
    }
}

__global__ __launch_bounds__(256) void k2_hist(const float* __restrict__ image,
                                               const float* __restrict__ depth,
                                               uint32_t* __restrict__ wsu) {
    __shared__ uint32_t s_hist[HIST_WORDS];
    __shared__ float s_chs[3*NSEG];
    for (int j = threadIdx.x; j < HIST_WORDS; j += 256) s_hist[j] = 0;
    if (threadIdx.x < 3*NSEG) s_chs[threadIdx.x] = 0.0f;
    __syncthreads();

    float dmin = __uint_as_float(wsu[WS_DMIN]);
    float dmax = __uint_as_float(wsu[WS_DMAX]);
    float invw = 10.0f / (dmax - dmin);

    const float4* r4 = (const float4*)image;
    const float4* g4 = (const float4*)(image + HWPX);
    const float4* b4 = (const float4*)(image + 2*HWPX);
    const float4* d4 = (const float4*)depth;
    int tid = blockIdx.x * 256 + threadIdx.x;
    int nth = gridDim.x * 256;
    for (int i = tid; i < HWPX/4; i += nth) {
        float4 rv = r4[i], gv = g4[i], bv = b4[i], dv = d4[i];
        float ra[4] = {rv.x, rv.y, rv.z, rv.w};
        float ga[4] = {gv.x, gv.y, gv.z, gv.w};
        float ba[4] = {bv.x, bv.y, bv.z, bv.w};
        float da[4] = {dv.x, dv.y, dv.z, dv.w};
        #pragma unroll
        for (int j = 0; j < 4; ++j) {
            int sg = seg_of(da[j], dmin, dmax, invw);
            if (sg < NSEG) {
                float m = fminf(ra[j], fminf(ga[j], ba[j]));
                int bin = (m < LOWR) ? (int)(m * INV_LOWW) : NB;
                atomicAdd(&s_hist[sg*(NB+1) + bin], 1u);
                atomicAdd(&s_chs[sg*3+0], ra[j]);
                atomicAdd(&s_chs[sg*3+1], ga[j]);
                atomicAdd(&s_chs[sg*3+2], ba[j]);
            }
        }
    }
    __syncthreads();
    float* wsf = (float*)wsu;
    for (int j = threadIdx.x; j < HIST_WORDS; j += 256) {
        uint32_t c = s_hist[j];
        if (c) atomicAdd(&wsu[WS_HIST + j], c);
    }
    if (threadIdx.x < 3*NSEG) atomicAdd(&wsf[WS_CHS + threadIdx.x], s_chs[threadIdx.x]);
}

__global__ void k3_stats(uint32_t* __restrict__ wsu) {
    __shared__ uint32_t sh[HIST_WORDS];
    for (int j = threadIdx.x; j < HIST_WORDS; j += blockDim.x) sh[j] = wsu[WS_HIST + j];
    __syncthreads();
    float* wsf = (float*)wsu;
    int s = threadIdx.x;
    if (s < NSEG) {
        const uint32_t* h = &sh[s*(NB+1)];
        uint32_t n = 0;
        for (int b = 0; b <= NB; ++b) n += h[b];
        uint32_t k = n / 100;                 // n * BOTTOM_PCT // 100
        float bsum = 0.0f; uint32_t taken = 0;
        for (int b = 0; b < NB; ++b) {
            uint32_t rem = k - taken;         // invariant: taken <= k
            uint32_t c = h[b];
            uint32_t t = c < rem ? c : rem;
            bsum += (float)t * (((float)b + 0.5f) * BINW);
            taken += t;
        }
        if (taken < k) bsum += (float)(k - taken) * LOWR;   // fallback, shouldn't hit
        float B = (k > 0) ? (bsum / (float)k) : 0.0f;
        float fn = (float)n;
        wsf[WS_DSEG + s*4 + 0] = wsf[WS_CHS + s*3 + 0] / fn - B;
        wsf[WS_DSEG + s*4 + 1] = wsf[WS_CHS + s*3 + 1] / fn - B;
        wsf[WS_DSEG + s*4 + 2] = wsf[WS_CHS + s*3 + 2] / fn - B;
        wsf[WS_DSEG + s*4 + 3] = 0.0f;
    } else if (s == NSEG) {
        wsf[WS_DSEG + 40] = 0.0f; wsf[WS_DSEG + 41] = 0.0f;
        wsf[WS_DSEG + 42] = 0.0f; wsf[WS_DSEG + 43] = 0.0f;
    }
}

__global__ __launch_bounds__(256) void k4_out(const float* __restrict__ image,
                                              const float* __restrict__ depth,
                                              const float* __restrict__ mu0p,
                                              const float* __restrict__ mu1p,
                                              const float* __restrict__ mu2p,
                                              const uint32_t* __restrict__ wsu,
                                              float* __restrict__ out) {
    __shared__ float4 s_D4[NSEG+1];
    const float* wsf = (const float*)wsu;
    if (threadIdx.x < NSEG+1)
        s_D4[threadIdx.x] = ((const float4*)(wsf + WS_DSEG))[threadIdx.x];
    __syncthreads();

    float dmin = __uint_as_float(wsu[WS_DMIN]);
    float dmax = __uint_as_float(wsu[WS_DMAX]);
    float invw = 10.0f / (dmax - dmin);
    float mu0 = *mu0p, mu1 = *mu1p, mu2 = *mu2p;

    int gid = blockIdx.x * 256 + threadIdx.x;       // one 4-px quad per thread
    int row = gid >> 9;                              // / (WW/4)
    int col = (gid & 511) << 2;

    float nd[3][6];
    #pragma unroll
    for (int rr = 0; rr < 3; ++rr) {
        int r2 = row + rr - 1;
        if (r2 >= 0 && r2 < HH) {
            const float* dp = depth + (size_t)r2 * WW + col;
            float4 m = *(const float4*)dp;
            nd[rr][1] = m.x; nd[rr][2] = m.y; nd[rr][3] = m.z; nd[rr][4] = m.w;
            nd[rr][0] = (col > 0)      ? dp[-1] : INFINITY;
            nd[rr][5] = (col + 4 < WW) ? dp[4]  : INFINITY;
        } else {
            #pragma unroll
            for (int cc = 0; cc < 6; ++cc) nd[rr][cc] = INFINITY;
        }
    }
    // per-entry D lookup (INF -> seg 10 -> zeros; masked anyway)
    float4 Dv[3][6];
    #pragma unroll
    for (int rr = 0; rr < 3; ++rr) {
        #pragma unroll
        for (int cc = 0; cc < 6; ++cc) {
            int si = seg_of(nd[rr][cc], dmin, dmax, invw);
            Dv[rr][cc] = s_D4[si];
        }
    }
    size_t base = (size_t)row * WW + col;
    float4 rv = *(const float4*)(image + base);
    float4 gv = *(const float4*)(image + HWPX + base);
    float4 bv = *(const float4*)(image + 2*HWPX + base);
    float ra[4] = {rv.x, rv.y, rv.z, rv.w};
    float ga[4] = {gv.x, gv.y, gv.z, gv.w};
    float ba[4] = {bv.x, bv.y, bv.z, bv.w};
    float o0[4], o1[4], o2[4];
    #pragma unroll
    for (int j = 0; j < 4; ++j) {
        float dc = nd[1][j+1];
        float cnt = 0.0f, a0 = 0.0f, a1 = 0.0f, a2 = 0.0f;
        #pragma unroll
        for (int rr = 0; rr < 3; ++rr) {
            #pragma unroll
            for (int dx = 0; dx < 3; ++dx) {
                float nv = nd[rr][j+dx];
                float msk = (fabsf(nv - dc) < 1.0f) ? 1.0f : 0.0f;
                float4 dd = Dv[rr][j+dx];
                cnt += msk; a0 += msk*dd.x; a1 += msk*dd.y; a2 += msk*dd.z;
            }
        }
        float rc = 1.0f / cnt;                    // cnt >= 1 (center always valid)
        float4 Dc = Dv[1][j+1];
        float dval = mu0 + mu1 * fmaxf(ga[j], ba[j]) + mu2 * ra[j];
        // E = F_SCALE*(P_MIX*D + (1-P_MIX)*a') = D + a'; J = E*d
        o0[j] = (Dc.x + a0*rc) * dval;
        o1[j] = (Dc.y + a1*rc) * dval;
        o2[j] = (Dc.z + a2*rc) * dval;
    }
    *(float4*)(out + base)          = make_float4(o0[0], o0[1], o0[2], o0[3]);
    *(float4*)(out + HWPX + base)   = make_float4(o1[0], o1[1], o1[2], o1[3]);
    *(float4*)(out + 2*HWPX + base) = make_float4(o2[0], o2[1], o2[2], o2[3]);
}

extern "C" void kernel_launch(void* const* d_in, const int* in_sizes, int n_in,
                              void* d_out, int out_size, void* d_ws, size_t ws_size,
                              hipStream_t stream) {
    const float* image = (const float*)d_in[0];
    const float* depth = (const float*)d_in[1];
    const float* mu0   = (const float*)d_in[2];
    const float* mu1   = (const float*)d_in[3];
    const float* mu2   = (const float*)d_in[4];
    uint32_t* wsu = (uint32_t*)d_ws;
    float* out = (float*)d_out;

    hipLaunchKernelGGL(k0_init,   dim3(8),    dim3(256), 0, stream, wsu);
    hipLaunchKernelGGL(k1_minmax, dim3(1024), dim3(256), 0, stream, depth, wsu);
    hipLaunchKernelGGL(k2_hist,   dim3(1024), dim3(256), 0, stream, image, depth, wsu);
    hipLaunchKernelGGL(k3_stats,  dim3(1),    dim3(256), 0, stream, wsu);
    hipLaunchKernelGGL(k4_out,    dim3((HWPX/4)/256), dim3(256), 0, stream,
                       image, depth, mu0, mu1, mu2, wsu, out);
}

// Round 2
// 194.922 us; speedup vs baseline: 1.2299x; 1.2299x over previous
//
#include <hip/hip_runtime.h>
#include <cstdint>
#include <math.h>

#define HH 2048
#define WW 2048
#define HWPX (HH*WW)
#define NSEG 10
#define NB 256
#define LOWR 0.0625f
#define INV_LOWW 4096.0f           // NB / LOWR
#define BINW (LOWR/(float)NB)

// workspace layout (32-bit words)
#define WS_DMIN 0
#define WS_DMAX 1
#define WS_HIST 2                          // NSEG*NB uints (only m < LOWR binned)
#define HIST_WORDS (NSEG*NB)               // 2560
#define WS_ACC (WS_HIST + HIST_WORDS)      // 2562: 40 floats [cnt0..9, r0..9, g0..9, b0..9]
#define WS_DSEG 2604                       // 16B-aligned: 11 float4 (seg 10 = zeros)
#define WS_TOTAL (WS_DSEG + 44)

// Segment rule: replicates bins = linspace(dmin,dmax,11); pixel in seg s iff
// bins[s] <= v < bins[s+1]. v == dmax (== bins[10]) is in NO segment -> 10.
__device__ __forceinline__ int seg_of(float v, float dmin, float dmax, float invw) {
    int sg = (int)((v - dmin) * invw);   // v>=dmin; INF saturates then masked below
    sg = sg > (NSEG-1) ? (NSEG-1) : sg;
    return (v >= dmax) ? NSEG : sg;
}

__global__ void k0_init(uint32_t* __restrict__ wsu) {
    int nth = gridDim.x * blockDim.x;
    int i = blockIdx.x * blockDim.x + threadIdx.x;
    for (int j = i; j < WS_TOTAL; j += nth) {
        uint32_t v = 0;
        if (j == WS_DMIN) v = 0x7F800000u;   // +inf
        // WS_DMAX init 0 (0.0f) ok: depth >= 0
        wsu[j] = v;
    }
}

__global__ __launch_bounds__(256) void k1_minmax(const float* __restrict__ depth,
                                                 uint32_t* __restrict__ wsu) {
    int tid = blockIdx.x * 256 + threadIdx.x;
    int nth = gridDim.x * 256;
    float vmin = INFINITY, vmax = 0.0f;
    const float4* d4 = (const float4*)depth;
    for (int i = tid; i < HWPX/4; i += nth) {
        float4 v = d4[i];
        vmin = fminf(vmin, fminf(fminf(v.x, v.y), fminf(v.z, v.w)));
        vmax = fmaxf(vmax, fmaxf(fmaxf(v.x, v.y), fmaxf(v.z, v.w)));
    }
    #pragma unroll
    for (int off = 32; off > 0; off >>= 1) {
        vmin = fminf(vmin, __shfl_down(vmin, off, 64));
        vmax = fmaxf(vmax, __shfl_down(vmax, off, 64));
    }
    __shared__ float smin[4], smax[4];
    int wid = threadIdx.x >> 6;
    if ((threadIdx.x & 63) == 0) { smin[wid] = vmin; smax[wid] = vmax; }
    __syncthreads();
    if (threadIdx.x == 0) {
        float bmin = fminf(fminf(smin[0], smin[1]), fminf(smin[2], smin[3]));
        float bmax = fmaxf(fmaxf(smax[0], smax[1]), fmaxf(smax[2], smax[3]));
        atomicMin(&wsu[WS_DMIN], __float_as_uint(bmin));   // depth>=0: bits ordered
        atomicMax(&wsu[WS_DMAX], __float_as_uint(bmax));
    }
}

// Per-segment {count, sum_r, sum_g, sum_b} in per-thread registers (static-index
// unrolled select: no LDS atomic contention). Histogram LDS atomics only for
// m < LOWR (~18% of pixels, spread over 2560 bins).
__global__ __launch_bounds__(256) void k2_hist(const float* __restrict__ image,
                                               const float* __restrict__ depth,
                                               uint32_t* __restrict__ wsu) {
    __shared__ uint32_t s_hist[HIST_WORDS];
    __shared__ float s_red[4][40];
    for (int j = threadIdx.x; j < HIST_WORDS; j += 256) s_hist[j] = 0;
    __syncthreads();

    float dmin = __uint_as_float(wsu[WS_DMIN]);
    float dmax = __uint_as_float(wsu[WS_DMAX]);
    float invw = 10.0f / (dmax - dmin);

    float c_cnt[NSEG], c_r[NSEG], c_g[NSEG], c_b[NSEG];
    #pragma unroll
    for (int s = 0; s < NSEG; ++s) { c_cnt[s]=0.f; c_r[s]=0.f; c_g[s]=0.f; c_b[s]=0.f; }

    const float4* r4 = (const float4*)image;
    const float4* g4 = (const float4*)(image + HWPX);
    const float4* b4 = (const float4*)(image + 2*HWPX);
    const float4* d4 = (const float4*)depth;
    int tid = blockIdx.x * 256 + threadIdx.x;
    int nth = gridDim.x * 256;
    for (int i = tid; i < HWPX/4; i += nth) {
        float4 rv = r4[i], gv = g4[i], bv = b4[i], dv = d4[i];
        float ra[4] = {rv.x, rv.y, rv.z, rv.w};
        float ga[4] = {gv.x, gv.y, gv.z, gv.w};
        float ba[4] = {bv.x, bv.y, bv.z, bv.w};
        float da[4] = {dv.x, dv.y, dv.z, dv.w};
        #pragma unroll
        for (int j = 0; j < 4; ++j) {
            int sg = seg_of(da[j], dmin, dmax, invw);
            float m = fminf(ra[j], fminf(ga[j], ba[j]));
            if (sg < NSEG && m < LOWR) {
                atomicAdd(&s_hist[sg*NB + (int)(m * INV_LOWW)], 1u);
            }
            #pragma unroll
            for (int s = 0; s < NSEG; ++s) {
                float sel = (sg == s) ? 1.0f : 0.0f;
                c_cnt[s] += sel;
                c_r[s] += sel * ra[j];
                c_g[s] += sel * ga[j];
                c_b[s] += sel * ba[j];
            }
        }
    }
    // wave reduction of the 40 accumulators
    #pragma unroll
    for (int s = 0; s < NSEG; ++s) {
        #pragma unroll
        for (int off = 32; off > 0; off >>= 1) {
            c_cnt[s] += __shfl_down(c_cnt[s], off, 64);
            c_r[s]   += __shfl_down(c_r[s],   off, 64);
            c_g[s]   += __shfl_down(c_g[s],   off, 64);
            c_b[s]   += __shfl_down(c_b[s],   off, 64);
        }
    }
    int wid = threadIdx.x >> 6;
    if ((threadIdx.x & 63) == 0) {
        #pragma unroll
        for (int s = 0; s < NSEG; ++s) {
            s_red[wid][s]      = c_cnt[s];
            s_red[wid][10 + s] = c_r[s];
            s_red[wid][20 + s] = c_g[s];
            s_red[wid][30 + s] = c_b[s];
        }
    }
    __syncthreads();
    float* wsf = (float*)wsu;
    if (threadIdx.x < 40) {
        float v = s_red[0][threadIdx.x] + s_red[1][threadIdx.x]
                + s_red[2][threadIdx.x] + s_red[3][threadIdx.x];
        atomicAdd(&wsf[WS_ACC + threadIdx.x], v);
    }
    for (int j = threadIdx.x; j < HIST_WORDS; j += 256) {
        uint32_t c = s_hist[j];
        if (c) atomicAdd(&wsu[WS_HIST + j], c);
    }
}

__global__ void k3_stats(uint32_t* __restrict__ wsu) {
    __shared__ uint32_t sh[HIST_WORDS];
    for (int j = threadIdx.x; j < HIST_WORDS; j += blockDim.x) sh[j] = wsu[WS_HIST + j];
    __syncthreads();
    float* wsf = (float*)wsu;
    int s = threadIdx.x;
    if (s < NSEG) {
        float fn = wsf[WS_ACC + s];                // exact integer-valued float
        uint32_t n = (uint32_t)(fn + 0.5f);
        uint32_t k = n / 100;                      // n * BOTTOM_PCT // 100
        const uint32_t* h = &sh[s*NB];
        float bsum = 0.0f; uint32_t taken = 0;
        for (int b = 0; b < NB; ++b) {
            uint32_t rem = k - taken;              // invariant: taken <= k
            uint32_t c = h[b];
            uint32_t t = c < rem ? c : rem;
            bsum += (float)t * (((float)b + 0.5f) * BINW);
            taken += t;
        }
        if (taken < k) bsum += (float)(k - taken) * LOWR;   // fallback, shouldn't hit
        float B = (k > 0) ? (bsum / (float)k) : 0.0f;
        wsf[WS_DSEG + s*4 + 0] = wsf[WS_ACC + 10 + s] / fn - B;
        wsf[WS_DSEG + s*4 + 1] = wsf[WS_ACC + 20 + s] / fn - B;
        wsf[WS_DSEG + s*4 + 2] = wsf[WS_ACC + 30 + s] / fn - B;
        wsf[WS_DSEG + s*4 + 3] = 0.0f;
    } else if (s == NSEG) {
        wsf[WS_DSEG + 40] = 0.0f; wsf[WS_DSEG + 41] = 0.0f;
        wsf[WS_DSEG + 42] = 0.0f; wsf[WS_DSEG + 43] = 0.0f;
    }
}

__global__ __launch_bounds__(256) void k4_out(const float* __restrict__ image,
                                              const float* __restrict__ depth,
                                              const float* __restrict__ mu0p,
                                              const float* __restrict__ mu1p,
                                              const float* __restrict__ mu2p,
                                              const uint32_t* __restrict__ wsu,
                                              float* __restrict__ out) {
    __shared__ float4 s_D4[NSEG+1];
    const float* wsf = (const float*)wsu;
    if (threadIdx.x < NSEG+1)
        s_D4[threadIdx.x] = ((const float4*)(wsf + WS_DSEG))[threadIdx.x];
    __syncthreads();

    float dmin = __uint_as_float(wsu[WS_DMIN]);
    float dmax = __uint_as_float(wsu[WS_DMAX]);
    float invw = 10.0f / (dmax - dmin);
    float mu0 = *mu0p, mu1 = *mu1p, mu2 = *mu2p;

    int gid = blockIdx.x * 256 + threadIdx.x;       // one 4-px quad per thread
    int row = gid >> 9;                              // / (WW/4)
    int col = (gid & 511) << 2;

    float nd[3][6];
    #pragma unroll
    for (int rr = 0; rr < 3; ++rr) {
        int r2 = row + rr - 1;
        if (r2 >= 0 && r2 < HH) {
            const float* dp = depth + (size_t)r2 * WW + col;
            float4 m = *(const float4*)dp;
            nd[rr][1] = m.x; nd[rr][2] = m.y; nd[rr][3] = m.z; nd[rr][4] = m.w;
            nd[rr][0] = (col > 0)      ? dp[-1] : INFINITY;
            nd[rr][5] = (col + 4 < WW) ? dp[4]  : INFINITY;
        } else {
            #pragma unroll
            for (int cc = 0; cc < 6; ++cc) nd[rr][cc] = INFINITY;
        }
    }
    // per-entry D lookup (INF -> seg 10 -> zeros; masked anyway)
    float4 Dv[3][6];
    #pragma unroll
    for (int rr = 0; rr < 3; ++rr) {
        #pragma unroll
        for (int cc = 0; cc < 6; ++cc) {
            int si = seg_of(nd[rr][cc], dmin, dmax, invw);
            Dv[rr][cc] = s_D4[si];
        }
    }
    size_t base = (size_t)row * WW + col;
    float4 rv = *(const float4*)(image + base);
    float4 gv = *(const float4*)(image + HWPX + base);
    float4 bv = *(const float4*)(image + 2*HWPX + base);
    float ra[4] = {rv.x, rv.y, rv.z, rv.w};
    float ga[4] = {gv.x, gv.y, gv.z, gv.w};
    float ba[4] = {bv.x, bv.y, bv.z, bv.w};
    float o0[4], o1[4], o2[4];
    #pragma unroll
    for (int j = 0; j < 4; ++j) {
        float dc = nd[1][j+1];
        float cnt = 0.0f, a0 = 0.0f, a1 = 0.0f, a2 = 0.0f;
        #pragma unroll
        for (int rr = 0; rr < 3; ++rr) {
            #pragma unroll
            for (int dx = 0; dx < 3; ++dx) {
                float nv = nd[rr][j+dx];
                float msk = (fabsf(nv - dc) < 1.0f) ? 1.0f : 0.0f;
                float4 dd = Dv[rr][j+dx];
                cnt += msk; a0 += msk*dd.x; a1 += msk*dd.y; a2 += msk*dd.z;
            }
        }
        float rc = 1.0f / cnt;                    // cnt >= 1 (center always valid)
        float4 Dc = Dv[1][j+1];
        float dval = mu0 + mu1 * fmaxf(ga[j], ba[j]) + mu2 * ra[j];
        // E = F_SCALE*(P_MIX*D + (1-P_MIX)*a') = D + a'; J = E*d
        o0[j] = (Dc.x + a0*rc) * dval;
        o1[j] = (Dc.y + a1*rc) * dval;
        o2[j] = (Dc.z + a2*rc) * dval;
    }
    *(float4*)(out + base)          = make_float4(o0[0], o0[1], o0[2], o0[3]);
    *(float4*)(out + HWPX + base)   = make_float4(o1[0], o1[1], o1[2], o1[3]);
    *(float4*)(out + 2*HWPX + base) = make_float4(o2[0], o2[1], o2[2], o2[3]);
}

extern "C" void kernel_launch(void* const* d_in, const int* in_sizes, int n_in,
                              void* d_out, int out_size, void* d_ws, size_t ws_size,
                              hipStream_t stream) {
    const float* image = (const float*)d_in[0];
    const float* depth = (const float*)d_in[1];
    const float* mu0   = (const float*)d_in[2];
    const float* mu1   = (const float*)d_in[3];
    const float* mu2   = (const float*)d_in[4];
    uint32_t* wsu = (uint32_t*)d_ws;
    float* out = (float*)d_out;

    hipLaunchKernelGGL(k0_init,   dim3(8),    dim3(256), 0, stream, wsu);
    hipLaunchKernelGGL(k1_minmax, dim3(1024), dim3(256), 0, stream, depth, wsu);
    hipLaunchKernelGGL(k2_hist,   dim3(1024), dim3(256), 0, stream, image, depth, wsu);
    hipLaunchKernelGGL(k3_stats,  dim3(1),    dim3(256), 0, stream, wsu);
    hipLaunchKernelGGL(k4_out,    dim3((HWPX/4)/256), dim3(256), 0, stream,
                       image, depth, mu0, mu1, mu2, wsu, out);
}

// Round 3
// 190.755 us; speedup vs baseline: 1.2568x; 1.0218x over previous
//
#include <hip/hip_runtime.h>
#include <cstdint>
#include <math.h>

#define HH 2048
#define WW 2048
#define HWPX (HH*WW)
#define NSEG 10
#define NB 128
#define LOWR 0.03125f
#define INV_LOWW 4096.0f           // NB / LOWR (unchanged bin width vs R1)
#define BINW (LOWR/(float)NB)      // 2.441e-4

// workspace layout (32-bit words)
#define WS_DMIN 0
#define WS_DMAX 1
#define WS_HIST 2                          // NSEG*NB uints (only m < LOWR binned)
#define HIST_WORDS (NSEG*NB)               // 1280
#define WS_ACC (WS_HIST + HIST_WORDS)      // 1282: 40 floats [cnt0..9, r0..9, g0..9, b0..9]
#define WS_DSEG 1324                       // 16B-aligned: 11 float4 (seg 10 = zeros)
#define WS_TOTAL (WS_DSEG + 44)

// Segment rule: replicates bins = linspace(dmin,dmax,11); pixel in seg s iff
// bins[s] <= v < bins[s+1]. v == dmax (== bins[10]) is in NO segment -> 10.
__device__ __forceinline__ int seg_of(float v, float dmin, float dmax, float invw) {
    int sg = (int)((v - dmin) * invw);   // v>=dmin; INF saturates then masked below
    sg = sg > (NSEG-1) ? (NSEG-1) : sg;
    return (v >= dmax) ? NSEG : sg;
}

__global__ void k0_init(uint32_t* __restrict__ wsu) {
    int nth = gridDim.x * blockDim.x;
    int i = blockIdx.x * blockDim.x + threadIdx.x;
    for (int j = i; j < WS_TOTAL; j += nth) {
        uint32_t v = 0;
        if (j == WS_DMIN) v = 0x7F800000u;   // +inf
        wsu[j] = v;
    }
}

__global__ __launch_bounds__(256) void k1_minmax(const float* __restrict__ depth,
                                                 uint32_t* __restrict__ wsu) {
    int tid = blockIdx.x * 256 + threadIdx.x;
    int nth = gridDim.x * 256;
    float vmin = INFINITY, vmax = 0.0f;
    const float4* d4 = (const float4*)depth;
    for (int i = tid; i < HWPX/4; i += nth) {
        float4 v = d4[i];
        vmin = fminf(vmin, fminf(fminf(v.x, v.y), fminf(v.z, v.w)));
        vmax = fmaxf(vmax, fmaxf(fmaxf(v.x, v.y), fmaxf(v.z, v.w)));
    }
    #pragma unroll
    for (int off = 32; off > 0; off >>= 1) {
        vmin = fminf(vmin, __shfl_down(vmin, off, 64));
        vmax = fmaxf(vmax, __shfl_down(vmax, off, 64));
    }
    __shared__ float smin[4], smax[4];
    int wid = threadIdx.x >> 6;
    if ((threadIdx.x & 63) == 0) { smin[wid] = vmin; smax[wid] = vmax; }
    __syncthreads();
    if (threadIdx.x == 0) {
        float bmin = fminf(fminf(smin[0], smin[1]), fminf(smin[2], smin[3]));
        float bmax = fmaxf(fmaxf(smax[0], smax[1]), fmaxf(smax[2], smax[3]));
        atomicMin(&wsu[WS_DMIN], __float_as_uint(bmin));   // depth>=0: bits ordered
        atomicMax(&wsu[WS_DMAX], __float_as_uint(bmax));
    }
}

// Per-segment {count, sum_r, sum_g, sum_b} in per-thread registers.
// __launch_bounds__(256,2): allow up to 256 VGPRs so the 40 accumulators
// NEVER spill to scratch (suspected R1 residual cost).
__global__ __launch_bounds__(256, 2) void k2_hist(const float* __restrict__ image,
                                                  const float* __restrict__ depth,
                                                  uint32_t* __restrict__ wsu) {
    __shared__ uint32_t s_hist[HIST_WORDS];
    __shared__ float s_red[4][40];
    for (int j = threadIdx.x; j < HIST_WORDS; j += 256) s_hist[j] = 0;
    __syncthreads();

    float dmin = __uint_as_float(wsu[WS_DMIN]);
    float dmax = __uint_as_float(wsu[WS_DMAX]);
    float invw = 10.0f / (dmax - dmin);

    float c_cnt[NSEG], c_r[NSEG], c_g[NSEG], c_b[NSEG];
    #pragma unroll
    for (int s = 0; s < NSEG; ++s) { c_cnt[s]=0.f; c_r[s]=0.f; c_g[s]=0.f; c_b[s]=0.f; }

    const float4* r4 = (const float4*)image;
    const float4* g4 = (const float4*)(image + HWPX);
    const float4* b4 = (const float4*)(image + 2*HWPX);
    const float4* d4 = (const float4*)depth;
    int tid = blockIdx.x * 256 + threadIdx.x;
    int nth = gridDim.x * 256;
    for (int i = tid; i < HWPX/4; i += nth) {
        float4 rv = r4[i], gv = g4[i], bv = b4[i], dv = d4[i];
        float ra[4] = {rv.x, rv.y, rv.z, rv.w};
        float ga[4] = {gv.x, gv.y, gv.z, gv.w};
        float ba[4] = {bv.x, bv.y, bv.z, bv.w};
        float da[4] = {dv.x, dv.y, dv.z, dv.w};
        #pragma unroll
        for (int j = 0; j < 4; ++j) {
            int sg = seg_of(da[j], dmin, dmax, invw);
            float m = fminf(ra[j], fminf(ga[j], ba[j]));
            if (sg < NSEG && m < LOWR) {
                atomicAdd(&s_hist[sg*NB + (int)(m * INV_LOWW)], 1u);
            }
            #pragma unroll
            for (int s = 0; s < NSEG; ++s) {
                float sel = (sg == s) ? 1.0f : 0.0f;
                c_cnt[s] += sel;
                c_r[s] += sel * ra[j];
                c_g[s] += sel * ga[j];
                c_b[s] += sel * ba[j];
            }
        }
    }
    // wave reduction of the 40 accumulators
    #pragma unroll
    for (int s = 0; s < NSEG; ++s) {
        #pragma unroll
        for (int off = 32; off > 0; off >>= 1) {
            c_cnt[s] += __shfl_down(c_cnt[s], off, 64);
            c_r[s]   += __shfl_down(c_r[s],   off, 64);
            c_g[s]   += __shfl_down(c_g[s],   off, 64);
            c_b[s]   += __shfl_down(c_b[s],   off, 64);
        }
    }
    int wid = threadIdx.x >> 6;
    if ((threadIdx.x & 63) == 0) {
        #pragma unroll
        for (int s = 0; s < NSEG; ++s) {
            s_red[wid][s]      = c_cnt[s];
            s_red[wid][10 + s] = c_r[s];
            s_red[wid][20 + s] = c_g[s];
            s_red[wid][30 + s] = c_b[s];
        }
    }
    __syncthreads();
    float* wsf = (float*)wsu;
    if (threadIdx.x < 40) {
        float v = s_red[0][threadIdx.x] + s_red[1][threadIdx.x]
                + s_red[2][threadIdx.x] + s_red[3][threadIdx.x];
        atomicAdd(&wsf[WS_ACC + threadIdx.x], v);
    }
    for (int j = threadIdx.x; j < HIST_WORDS; j += 256) {
        uint32_t c = s_hist[j];
        if (c) atomicAdd(&wsu[WS_HIST + j], c);
    }
}

__global__ void k3_stats(uint32_t* __restrict__ wsu) {
    __shared__ uint32_t sh[HIST_WORDS];
    for (int j = threadIdx.x; j < HIST_WORDS; j += blockDim.x) sh[j] = wsu[WS_HIST + j];
    __syncthreads();
    float* wsf = (float*)wsu;
    int s = threadIdx.x;
    if (s < NSEG) {
        float fn = wsf[WS_ACC + s];                // exact integer-valued float
        uint32_t n = (uint32_t)(fn + 0.5f);
        uint32_t k = n / 100;                      // n * BOTTOM_PCT // 100
        const uint32_t* h = &sh[s*NB];
        float bsum = 0.0f; uint32_t taken = 0;
        for (int b = 0; b < NB; ++b) {
            uint32_t rem = k - taken;              // invariant: taken <= k
            uint32_t c = h[b];
            uint32_t t = c < rem ? c : rem;
            bsum += (float)t * (((float)b + 0.5f) * BINW);
            taken += t;
        }
        if (taken < k) bsum += (float)(k - taken) * LOWR;   // fallback, shouldn't hit
        float B = (k > 0) ? (bsum / (float)k) : 0.0f;
        wsf[WS_DSEG + s*4 + 0] = wsf[WS_ACC + 10 + s] / fn - B;
        wsf[WS_DSEG + s*4 + 1] = wsf[WS_ACC + 20 + s] / fn - B;
        wsf[WS_DSEG + s*4 + 2] = wsf[WS_ACC + 30 + s] / fn - B;
        wsf[WS_DSEG + s*4 + 3] = 0.0f;
    } else if (s == NSEG) {
        wsf[WS_DSEG + 40] = 0.0f; wsf[WS_DSEG + 41] = 0.0f;
        wsf[WS_DSEG + 42] = 0.0f; wsf[WS_DSEG + 43] = 0.0f;
    }
}

// Per-entry D processing (no Dv[3][6] register cache -> no spill) + shfl halo
// (wave never straddles a row: 64 | 512 quads/row). Only lanes 0/63 load edges.
__global__ __launch_bounds__(256, 2) void k4_out(const float* __restrict__ image,
                                                 const float* __restrict__ depth,
                                                 const float* __restrict__ mu0p,
                                                 const float* __restrict__ mu1p,
                                                 const float* __restrict__ mu2p,
                                                 const uint32_t* __restrict__ wsu,
                                                 float* __restrict__ out) {
    __shared__ float4 s_D4[NSEG+1];
    const float* wsf = (const float*)wsu;
    if (threadIdx.x < NSEG+1)
        s_D4[threadIdx.x] = ((const float4*)(wsf + WS_DSEG))[threadIdx.x];
    __syncthreads();

    float dmin = __uint_as_float(wsu[WS_DMIN]);
    float dmax = __uint_as_float(wsu[WS_DMAX]);
    float invw = 10.0f / (dmax - dmin);
    float mu0 = *mu0p, mu1 = *mu1p, mu2 = *mu2p;

    int gid = blockIdx.x * 256 + threadIdx.x;       // one 4-px quad per thread
    int row = gid >> 9;                              // / (WW/4); uniform per wave
    int col = (gid & 511) << 2;
    int lane = threadIdx.x & 63;

    float nd[3][6];
    #pragma unroll
    for (int rr = 0; rr < 3; ++rr) {
        int r2 = row + rr - 1;
        if (r2 >= 0 && r2 < HH) {                    // wave-uniform branch
            const float* dp = depth + (size_t)r2 * WW + col;
            float4 m = *(const float4*)dp;
            float left  = __shfl_up(m.w, 1, 64);
            float right = __shfl_down(m.x, 1, 64);
            if (lane == 0)  left  = (col > 0)      ? dp[-1] : INFINITY;
            if (lane == 63) right = (col + 4 < WW) ? dp[4]  : INFINITY;
            nd[rr][0] = left;  nd[rr][1] = m.x; nd[rr][2] = m.y;
            nd[rr][3] = m.z;   nd[rr][4] = m.w; nd[rr][5] = right;
        } else {
            #pragma unroll
            for (int cc = 0; cc < 6; ++cc) nd[rr][cc] = INFINITY;
        }
    }

    float cnt[4], A0[4], A1[4], A2[4];
    #pragma unroll
    for (int j = 0; j < 4; ++j) { cnt[j]=0.f; A0[j]=0.f; A1[j]=0.f; A2[j]=0.f; }

    #pragma unroll
    for (int rr = 0; rr < 3; ++rr) {
        #pragma unroll
        for (int cc = 0; cc < 6; ++cc) {
            float nv = nd[rr][cc];
            float4 dd = s_D4[seg_of(nv, dmin, dmax, invw)];
            #pragma unroll
            for (int j = 0; j < 4; ++j) {
                if (j >= cc - 2 && j <= cc) {        // compile-time folded
                    float msk = (fabsf(nv - nd[1][j+1]) < 1.0f) ? 1.0f : 0.0f;
                    cnt[j] += msk; A0[j] += msk*dd.x; A1[j] += msk*dd.y; A2[j] += msk*dd.z;
                }
            }
        }
    }

    size_t base = (size_t)row * WW + col;
    float4 rv = *(const float4*)(image + base);
    float4 gv = *(const float4*)(image + HWPX + base);
    float4 bv = *(const float4*)(image + 2*HWPX + base);
    float ra[4] = {rv.x, rv.y, rv.z, rv.w};
    float ga[4] = {gv.x, gv.y, gv.z, gv.w};
    float ba[4] = {bv.x, bv.y, bv.z, bv.w};
    float o0[4], o1[4], o2[4];
    #pragma unroll
    for (int j = 0; j < 4; ++j) {
        float rc = 1.0f / cnt[j];                 // cnt >= 1 (center always valid)
        float4 Dc = s_D4[seg_of(nd[1][j+1], dmin, dmax, invw)];
        float dval = mu0 + mu1 * fmaxf(ga[j], ba[j]) + mu2 * ra[j];
        // E = F_SCALE*(P_MIX*D + (1-P_MIX)*a') = D + a'; J = E*d
        o0[j] = (Dc.x + A0[j]*rc) * dval;
        o1[j] = (Dc.y + A1[j]*rc) * dval;
        o2[j] = (Dc.z + A2[j]*rc) * dval;
    }
    *(float4*)(out + base)          = make_float4(o0[0], o0[1], o0[2], o0[3]);
    *(float4*)(out + HWPX + base)   = make_float4(o1[0], o1[1], o1[2], o1[3]);
    *(float4*)(out + 2*HWPX + base) = make_float4(o2[0], o2[1], o2[2], o2[3]);
}

extern "C" void kernel_launch(void* const* d_in, const int* in_sizes, int n_in,
                              void* d_out, int out_size, void* d_ws, size_t ws_size,
                              hipStream_t stream) {
    const float* image = (const float*)d_in[0];
    const float* depth = (const float*)d_in[1];
    const float* mu0   = (const float*)d_in[2];
    const float* mu1   = (const float*)d_in[3];
    const float* mu2   = (const float*)d_in[4];
    uint32_t* wsu = (uint32_t*)d_ws;
    float* out = (float*)d_out;

    hipLaunchKernelGGL(k0_init,   dim3(8),    dim3(256), 0, stream, wsu);
    hipLaunchKernelGGL(k1_minmax, dim3(1024), dim3(256), 0, stream, depth, wsu);
    hipLaunchKernelGGL(k2_hist,   dim3(1024), dim3(256), 0, stream, image, depth, wsu);
    hipLaunchKernelGGL(k3_stats,  dim3(1),    dim3(256), 0, stream, wsu);
    hipLaunchKernelGGL(k4_out,    dim3((HWPX/4)/256), dim3(256), 0, stream,
                       image, depth, mu0, mu1, mu2, wsu, out);
}

// Round 5
// 168.288 us; speedup vs baseline: 1.4246x; 1.1335x over previous
//
#include <hip/hip_runtime.h>
#include <cstdint>
#include <math.h>

#define HH 2048
#define WW 2048
#define HWPX (HH*WW)
#define NSEG 10
#define NB 128
#define LOWR 0.03125f
#define INV_LOWW 4096.0f           // NB / LOWR
#define BINW (LOWR/(float)NB)      // 2.441e-4

#define K2_BLOCKS 1024
#define SLICE_W 1320               // 1280 hist + 40 acc per block

typedef float vfloat4 __attribute__((ext_vector_type(4)));   // clang-native for nontemporal

// workspace layout (32-bit words)
#define WS_DMIN 0
#define WS_DMAX 1
#define WS_HIST 8                          // final hist: NSEG*NB = 1280 uints
#define HIST_WORDS (NSEG*NB)
#define WS_ACC (WS_HIST + HIST_WORDS)      // 1288: 40 floats [cnt0..9, r0..9, g0..9, b0..9]
#define WS_DSEG 1328                       // 16B-aligned: 11 float4
#define WS_SLICE 1408                      // per-block slices: K2_BLOCKS * SLICE_W words (5.4 MB)

// Segment rule: replicates bins = linspace(dmin,dmax,11); pixel in seg s iff
// bins[s] <= v < bins[s+1]. v == dmax (== bins[10]) is in NO segment -> 10.
__device__ __forceinline__ int seg_of(float v, float dmin, float dmax, float invw) {
    int sg = (int)((v - dmin) * invw);
    sg = sg > (NSEG-1) ? (NSEG-1) : sg;
    return (v >= dmax) ? NSEG : sg;
}

// zero final hist+acc (k3a atomically accumulates into them) + set dmin/dmax seeds
__global__ void k0_init(uint32_t* __restrict__ wsu) {
    int i = blockIdx.x * blockDim.x + threadIdx.x;
    int nth = gridDim.x * blockDim.x;
    for (int j = i; j < HIST_WORDS + 40; j += nth) wsu[WS_HIST + j] = 0;
    if (i == 0) { wsu[WS_DMIN] = 0x7F800000u; wsu[WS_DMAX] = 0u; }
}

__global__ __launch_bounds__(256) void k1_minmax(const float* __restrict__ depth,
                                                 uint32_t* __restrict__ wsu) {
    int tid = blockIdx.x * 256 + threadIdx.x;
    int nth = gridDim.x * 256;
    float vmin = INFINITY, vmax = 0.0f;
    const float4* d4 = (const float4*)depth;
    for (int i = tid; i < HWPX/4; i += nth) {
        float4 v = d4[i];
        vmin = fminf(vmin, fminf(fminf(v.x, v.y), fminf(v.z, v.w)));
        vmax = fmaxf(vmax, fmaxf(fmaxf(v.x, v.y), fmaxf(v.z, v.w)));
    }
    #pragma unroll
    for (int off = 32; off > 0; off >>= 1) {
        vmin = fminf(vmin, __shfl_down(vmin, off, 64));
        vmax = fmaxf(vmax, __shfl_down(vmax, off, 64));
    }
    __shared__ float smin[4], smax[4];
    int wid = threadIdx.x >> 6;
    if ((threadIdx.x & 63) == 0) { smin[wid] = vmin; smax[wid] = vmax; }
    __syncthreads();
    if (threadIdx.x == 0) {
        float bmin = fminf(fminf(smin[0], smin[1]), fminf(smin[2], smin[3]));
        float bmax = fmaxf(fmaxf(smax[0], smax[1]), fmaxf(smax[2], smax[3]));
        atomicMin(&wsu[WS_DMIN], __float_as_uint(bmin));   // depth>=0: bits ordered
        atomicMax(&wsu[WS_DMAX], __float_as_uint(bmax));
    }
}

// Register accumulators for per-seg stats; LDS hist only for m < LOWR (~9%).
// Flush: plain coalesced stores to a PRIVATE per-block slice (no global atomics).
__global__ __launch_bounds__(256, 2) void k2_hist(const float* __restrict__ image,
                                                  const float* __restrict__ depth,
                                                  uint32_t* __restrict__ wsu) {
    __shared__ uint32_t s_hist[HIST_WORDS];
    __shared__ float s_red[4][40];
    for (int j = threadIdx.x; j < HIST_WORDS; j += 256) s_hist[j] = 0;
    __syncthreads();

    float dmin = __uint_as_float(wsu[WS_DMIN]);
    float dmax = __uint_as_float(wsu[WS_DMAX]);
    float invw = 10.0f / (dmax - dmin);

    float c_cnt[NSEG], c_r[NSEG], c_g[NSEG], c_b[NSEG];
    #pragma unroll
    for (int s = 0; s < NSEG; ++s) { c_cnt[s]=0.f; c_r[s]=0.f; c_g[s]=0.f; c_b[s]=0.f; }

    const float4* r4 = (const float4*)image;
    const float4* g4 = (const float4*)(image + HWPX);
    const float4* b4 = (const float4*)(image + 2*HWPX);
    const float4* d4 = (const float4*)depth;
    int tid = blockIdx.x * 256 + threadIdx.x;
    int nth = K2_BLOCKS * 256;
    for (int i = tid; i < HWPX/4; i += nth) {
        float4 rv = r4[i], gv = g4[i], bv = b4[i], dv = d4[i];
        float ra[4] = {rv.x, rv.y, rv.z, rv.w};
        float ga[4] = {gv.x, gv.y, gv.z, gv.w};
        float ba[4] = {bv.x, bv.y, bv.z, bv.w};
        float da[4] = {dv.x, dv.y, dv.z, dv.w};
        #pragma unroll
        for (int j = 0; j < 4; ++j) {
            int sg = seg_of(da[j], dmin, dmax, invw);
            float m = fminf(ra[j], fminf(ga[j], ba[j]));
            if (sg < NSEG && m < LOWR) {
                atomicAdd(&s_hist[sg*NB + (int)(m * INV_LOWW)], 1u);
            }
            #pragma unroll
            for (int s = 0; s < NSEG; ++s) {
                float sel = (sg == s) ? 1.0f : 0.0f;
                c_cnt[s] += sel;
                c_r[s] += sel * ra[j];
                c_g[s] += sel * ga[j];
                c_b[s] += sel * ba[j];
            }
        }
    }
    #pragma unroll
    for (int s = 0; s < NSEG; ++s) {
        #pragma unroll
        for (int off = 32; off > 0; off >>= 1) {
            c_cnt[s] += __shfl_down(c_cnt[s], off, 64);
            c_r[s]   += __shfl_down(c_r[s],   off, 64);
            c_g[s]   += __shfl_down(c_g[s],   off, 64);
            c_b[s]   += __shfl_down(c_b[s],   off, 64);
        }
    }
    int wid = threadIdx.x >> 6;
    if ((threadIdx.x & 63) == 0) {
        #pragma unroll
        for (int s = 0; s < NSEG; ++s) {
            s_red[wid][s]      = c_cnt[s];
            s_red[wid][10 + s] = c_r[s];
            s_red[wid][20 + s] = c_g[s];
            s_red[wid][30 + s] = c_b[s];
        }
    }
    __syncthreads();
    uint32_t* slice = wsu + WS_SLICE + (size_t)blockIdx.x * SLICE_W;
    for (int j = threadIdx.x; j < HIST_WORDS; j += 256) slice[j] = s_hist[j];
    if (threadIdx.x < 40) {
        float v = s_red[0][threadIdx.x] + s_red[1][threadIdx.x]
                + s_red[2][threadIdx.x] + s_red[3][threadIdx.x];
        ((float*)slice)[HIST_WORDS + threadIdx.x] = v;
    }
}

// Reduce the K2_BLOCKS slices. blockIdx.x: which 256 columns; blockIdx.y: which
// 64 slices. 16 atomics per destination word (negligible contention).
__global__ __launch_bounds__(256) void k3a_reduce(uint32_t* __restrict__ wsu) {
    int j = blockIdx.x * 256 + threadIdx.x;
    if (j >= SLICE_W) return;
    int b0 = blockIdx.y * (K2_BLOCKS/16);
    if (j < HIST_WORDS) {
        uint32_t acc = 0;
        const uint32_t* p = wsu + WS_SLICE + (size_t)b0 * SLICE_W + j;
        #pragma unroll 4
        for (int b = 0; b < K2_BLOCKS/16; ++b) acc += p[(size_t)b * SLICE_W];
        if (acc) atomicAdd(&wsu[WS_HIST + j], acc);
    } else {
        float acc = 0.0f;
        const float* p = (const float*)(wsu + WS_SLICE + (size_t)b0 * SLICE_W + j);
        #pragma unroll 4
        for (int b = 0; b < K2_BLOCKS/16; ++b) acc += p[(size_t)b * SLICE_W];
        atomicAdd((float*)&wsu[WS_HIST + j], acc);   // WS_ACC region
    }
}

__global__ void k3b_stats(uint32_t* __restrict__ wsu) {
    __shared__ uint32_t sh[HIST_WORDS];
    for (int j = threadIdx.x; j < HIST_WORDS; j += blockDim.x) sh[j] = wsu[WS_HIST + j];
    __syncthreads();
    float* wsf = (float*)wsu;
    int s = threadIdx.x;
    if (s < NSEG) {
        float fn = wsf[WS_ACC + s];                // exact integer-valued float
        uint32_t n = (uint32_t)(fn + 0.5f);
        uint32_t k = n / 100;                      // n * BOTTOM_PCT // 100
        const uint32_t* h = &sh[s*NB];
        float bsum = 0.0f; uint32_t taken = 0;
        for (int b = 0; b < NB; ++b) {
            uint32_t rem = k - taken;
            uint32_t c = h[b];
            uint32_t t = c < rem ? c : rem;
            bsum += (float)t * (((float)b + 0.5f) * BINW);
            taken += t;
        }
        if (taken < k) bsum += (float)(k - taken) * LOWR;
        float B = (k > 0) ? (bsum / (float)k) : 0.0f;
        wsf[WS_DSEG + s*4 + 0] = wsf[WS_ACC + 10 + s] / fn - B;
        wsf[WS_DSEG + s*4 + 1] = wsf[WS_ACC + 20 + s] / fn - B;
        wsf[WS_DSEG + s*4 + 2] = wsf[WS_ACC + 30 + s] / fn - B;
        wsf[WS_DSEG + s*4 + 3] = 0.0f;
    } else if (s == NSEG) {
        wsf[WS_DSEG + 40] = 0.0f; wsf[WS_DSEG + 41] = 0.0f;
        wsf[WS_DSEG + 42] = 0.0f; wsf[WS_DSEG + 43] = 0.0f;
    }
}

__global__ __launch_bounds__(256, 2) void k4_out(const float* __restrict__ image,
                                                 const float* __restrict__ depth,
                                                 const float* __restrict__ mu0p,
                                                 const float* __restrict__ mu1p,
                                                 const float* __restrict__ mu2p,
                                                 const uint32_t* __restrict__ wsu,
                                                 float* __restrict__ out) {
    __shared__ float4 s_D4[NSEG+1];
    const float* wsf = (const float*)wsu;
    if (threadIdx.x < NSEG+1)
        s_D4[threadIdx.x] = ((const float4*)(wsf + WS_DSEG))[threadIdx.x];
    __syncthreads();

    float dmin = __uint_as_float(wsu[WS_DMIN]);
    float dmax = __uint_as_float(wsu[WS_DMAX]);
    float invw = 10.0f / (dmax - dmin);
    float mu0 = *mu0p, mu1 = *mu1p, mu2 = *mu2p;

    int gid = blockIdx.x * 256 + threadIdx.x;       // one 4-px quad per thread
    int row = gid >> 9;                              // uniform per wave
    int col = (gid & 511) << 2;
    int lane = threadIdx.x & 63;

    size_t base = (size_t)row * WW + col;
    float4 rv = *(const float4*)(image + base);
    float4 gv = *(const float4*)(image + HWPX + base);
    float4 bv = *(const float4*)(image + 2*HWPX + base);

    float nd[3][6];
    #pragma unroll
    for (int rr = 0; rr < 3; ++rr) {
        int r2 = row + rr - 1;
        if (r2 >= 0 && r2 < HH) {                    // wave-uniform branch
            const float* dp = depth + (size_t)r2 * WW + col;
            float4 m = *(const float4*)dp;
            float left  = __shfl_up(m.w, 1, 64);
            float right = __shfl_down(m.x, 1, 64);
            if (lane == 0)  left  = (col > 0)      ? dp[-1] : INFINITY;
            if (lane == 63) right = (col + 4 < WW) ? dp[4]  : INFINITY;
            nd[rr][0] = left;  nd[rr][1] = m.x; nd[rr][2] = m.y;
            nd[rr][3] = m.z;   nd[rr][4] = m.w; nd[rr][5] = right;
        } else {
            #pragma unroll
            for (int cc = 0; cc < 6; ++cc) nd[rr][cc] = INFINITY;
        }
    }

    float cnt[4], A0[4], A1[4], A2[4];
    #pragma unroll
    for (int j = 0; j < 4; ++j) { cnt[j]=0.f; A0[j]=0.f; A1[j]=0.f; A2[j]=0.f; }

    #pragma unroll
    for (int rr = 0; rr < 3; ++rr) {
        #pragma unroll
        for (int cc = 0; cc < 6; ++cc) {
            float nv = nd[rr][cc];
            float4 dd = s_D4[seg_of(nv, dmin, dmax, invw)];
            #pragma unroll
            for (int j = 0; j < 4; ++j) {
                if (j >= cc - 2 && j <= cc) {        // compile-time folded
                    float msk = (fabsf(nv - nd[1][j+1]) < 1.0f) ? 1.0f : 0.0f;
                    cnt[j] += msk; A0[j] += msk*dd.x; A1[j] += msk*dd.y; A2[j] += msk*dd.z;
                }
            }
        }
    }

    float ra[4] = {rv.x, rv.y, rv.z, rv.w};
    float ga[4] = {gv.x, gv.y, gv.z, gv.w};
    float ba[4] = {bv.x, bv.y, bv.z, bv.w};
    float o0[4], o1[4], o2[4];
    #pragma unroll
    for (int j = 0; j < 4; ++j) {
        float rc = 1.0f / cnt[j];
        float4 Dc = s_D4[seg_of(nd[1][j+1], dmin, dmax, invw)];
        float dval = mu0 + mu1 * fmaxf(ga[j], ba[j]) + mu2 * ra[j];
        o0[j] = (Dc.x + A0[j]*rc) * dval;
        o1[j] = (Dc.y + A1[j]*rc) * dval;
        o2[j] = (Dc.z + A2[j]*rc) * dval;
    }
    vfloat4 v0 = {o0[0], o0[1], o0[2], o0[3]};
    vfloat4 v1 = {o1[0], o1[1], o1[2], o1[3]};
    vfloat4 v2 = {o2[0], o2[1], o2[2], o2[3]};
    __builtin_nontemporal_store(v0, (vfloat4*)(out + base));
    __builtin_nontemporal_store(v1, (vfloat4*)(out + HWPX + base));
    __builtin_nontemporal_store(v2, (vfloat4*)(out + 2*HWPX + base));
}

extern "C" void kernel_launch(void* const* d_in, const int* in_sizes, int n_in,
                              void* d_out, int out_size, void* d_ws, size_t ws_size,
                              hipStream_t stream) {
    const float* image = (const float*)d_in[0];
    const float* depth = (const float*)d_in[1];
    const float* mu0   = (const float*)d_in[2];
    const float* mu1   = (const float*)d_in[3];
    const float* mu2   = (const float*)d_in[4];
    uint32_t* wsu = (uint32_t*)d_ws;
    float* out = (float*)d_out;

    hipLaunchKernelGGL(k0_init,    dim3(2),          dim3(256), 0, stream, wsu);
    hipLaunchKernelGGL(k1_minmax,  dim3(256),        dim3(256), 0, stream, depth, wsu);
    hipLaunchKernelGGL(k2_hist,    dim3(K2_BLOCKS),  dim3(256), 0, stream, image, depth, wsu);
    hipLaunchKernelGGL(k3a_reduce, dim3(6, 16),      dim3(256), 0, stream, wsu);
    hipLaunchKernelGGL(k3b_stats,  dim3(1),          dim3(256), 0, stream, wsu);
    hipLaunchKernelGGL(k4_out,     dim3((HWPX/4)/256), dim3(256), 0, stream,
                       image, depth, mu0, mu1, mu2, wsu, out);
}

// Round 8
// 158.724 us; speedup vs baseline: 1.5104x; 1.0603x over previous
//
#include <hip/hip_runtime.h>
#include <cstdint>
#include <math.h>

#define HH 2048
#define WW 2048
#define HWPX (HH*WW)
#define NSEG 10
#define NB 128
#define HIST_WORDS (NSEG*NB)       // 1280
#define LOWR 0.03125f
#define INV_LOWW 4096.0f           // NB / LOWR
#define BINW (LOWR/(float)NB)      // 2.441e-4

#define K2_BLOCKS 1024
#define SLICE_W 1320               // 1280 hist + 40 acc per block
#define NPART 16                   // k3a reduction fan-in stage

typedef float vfloat4 __attribute__((ext_vector_type(4)));

// workspace layout (32-bit words) — NO init kernel needed: everything below is
// written with plain stores before it is read (harness 0xAA poison is harmless).
#define WS_BMM 0                            // 512: k1 per-block min[256], max[256]
#define WS_PART 512                         // NPART * SLICE_W = 21120 partials
#define WS_DSEG 21632                       // 16B-aligned: 11 float4 (seg 10 = zeros)
#define WS_DMM (WS_DSEG + 44)               // dmin, dmax (written by k3b for k4)
#define WS_DVAL 21680                       // HWPX floats: dval staged k2 -> k4 (16.8 MB)
#define WS_SLICE (WS_DVAL + HWPX)           // K2_BLOCKS * SLICE_W (5.4 MB)

// Segment rule: replicates bins = linspace(dmin,dmax,11); pixel in seg s iff
// bins[s] <= v < bins[s+1]. v == dmax (== bins[10]) is in NO segment -> 10.
__device__ __forceinline__ int seg_of(float v, float dmin, float dmax, float invw) {
    int sg = (int)((v - dmin) * invw);
    sg = sg > (NSEG-1) ? (NSEG-1) : sg;
    return (v >= dmax) ? NSEG : sg;
}

// k1: per-block depth min/max -> plain stores (no atomics, no init required)
__global__ __launch_bounds__(256) void k1_minmax(const float* __restrict__ depth,
                                                 float* __restrict__ wsf) {
    int tid = blockIdx.x * 256 + threadIdx.x;
    int nth = gridDim.x * 256;
    float vmin = INFINITY, vmax = 0.0f;
    const float4* d4 = (const float4*)depth;
    for (int i = tid; i < HWPX/4; i += nth) {
        float4 v = d4[i];
        vmin = fminf(vmin, fminf(fminf(v.x, v.y), fminf(v.z, v.w)));
        vmax = fmaxf(vmax, fmaxf(fmaxf(v.x, v.y), fmaxf(v.z, v.w)));
    }
    #pragma unroll
    for (int off = 32; off > 0; off >>= 1) {
        vmin = fminf(vmin, __shfl_down(vmin, off, 64));
        vmax = fmaxf(vmax, __shfl_down(vmax, off, 64));
    }
    __shared__ float smin[4], smax[4];
    int wid = threadIdx.x >> 6;
    if ((threadIdx.x & 63) == 0) { smin[wid] = vmin; smax[wid] = vmax; }
    __syncthreads();
    if (threadIdx.x == 0) {
        wsf[WS_BMM + blockIdx.x]       = fminf(fminf(smin[0], smin[1]), fminf(smin[2], smin[3]));
        wsf[WS_BMM + 256 + blockIdx.x] = fmaxf(fmaxf(smax[0], smax[1]), fmaxf(smax[2], smax[3]));
    }
}

// Each block re-reduces k1's 512 per-block values (2 KB, L2-hot) to dmin/dmax.
__device__ __forceinline__ void block_minmax(const float* wsf, float& dmin, float& dmax,
                                             float smn[4], float smx[4]) {
    float v0 = wsf[WS_BMM + threadIdx.x];          // 256 block-mins
    float v1 = wsf[WS_BMM + 256 + threadIdx.x];    // 256 block-maxes
    #pragma unroll
    for (int off = 32; off > 0; off >>= 1) {
        v0 = fminf(v0, __shfl_down(v0, off, 64));
        v1 = fmaxf(v1, __shfl_down(v1, off, 64));
    }
    int wid = threadIdx.x >> 6;
    if ((threadIdx.x & 63) == 0) { smn[wid] = v0; smx[wid] = v1; }
    __syncthreads();
    dmin = fminf(fminf(smn[0], smn[1]), fminf(smn[2], smn[3]));
    dmax = fmaxf(fmaxf(smx[0], smx[1]), fmaxf(smx[2], smx[3]));
}

// k2: register per-seg stats; LDS hist only for m < LOWR (~9%); dval staged to
// ws for k4 (image is then never re-read). Flush: plain stores to private slice.
__global__ __launch_bounds__(256, 2) void k2_hist(const float* __restrict__ image,
                                                  const float* __restrict__ depth,
                                                  const float* __restrict__ mu0p,
                                                  const float* __restrict__ mu1p,
                                                  const float* __restrict__ mu2p,
                                                  uint32_t* __restrict__ wsu) {
    __shared__ uint32_t s_hist[HIST_WORDS];
    __shared__ float s_red[4][40];
    __shared__ float smn[4], smx[4];
    float* wsf = (float*)wsu;
    for (int j = threadIdx.x; j < HIST_WORDS; j += 256) s_hist[j] = 0;

    float dmin, dmax;
    block_minmax(wsf, dmin, dmax, smn, smx);       // includes the needed __syncthreads
    float invw = 10.0f / (dmax - dmin);
    float mu0 = *mu0p, mu1 = *mu1p, mu2 = *mu2p;

    float c_cnt[NSEG], c_r[NSEG], c_g[NSEG], c_b[NSEG];
    #pragma unroll
    for (int s = 0; s < NSEG; ++s) { c_cnt[s]=0.f; c_r[s]=0.f; c_g[s]=0.f; c_b[s]=0.f; }

    const float4* r4 = (const float4*)image;
    const float4* g4 = (const float4*)(image + HWPX);
    const float4* b4 = (const float4*)(image + 2*HWPX);
    const float4* d4 = (const float4*)depth;
    vfloat4* dval4 = (vfloat4*)(wsf + WS_DVAL);
    int tid = blockIdx.x * 256 + threadIdx.x;
    int nth = K2_BLOCKS * 256;
    for (int i = tid; i < HWPX/4; i += nth) {
        float4 rv = r4[i], gv = g4[i], bv = b4[i], dv = d4[i];
        float ra[4] = {rv.x, rv.y, rv.z, rv.w};
        float ga[4] = {gv.x, gv.y, gv.z, gv.w};
        float ba[4] = {bv.x, bv.y, bv.z, bv.w};
        float da[4] = {dv.x, dv.y, dv.z, dv.w};
        float dvo[4];
        #pragma unroll
        for (int j = 0; j < 4; ++j) {
            int sg = seg_of(da[j], dmin, dmax, invw);
            float m = fminf(ra[j], fminf(ga[j], ba[j]));
            if (sg < NSEG && m < LOWR) {
                atomicAdd(&s_hist[sg*NB + (int)(m * INV_LOWW)], 1u);
            }
            #pragma unroll
            for (int s = 0; s < NSEG; ++s) {
                float sel = (sg == s) ? 1.0f : 0.0f;
                c_cnt[s] += sel;
                c_r[s] += sel * ra[j];
                c_g[s] += sel * ga[j];
                c_b[s] += sel * ba[j];
            }
            dvo[j] = mu0 + mu1 * fmaxf(ga[j], ba[j]) + mu2 * ra[j];
        }
        vfloat4 dq = {dvo[0], dvo[1], dvo[2], dvo[3]};
        dval4[i] = dq;
    }
    #pragma unroll
    for (int s = 0; s < NSEG; ++s) {
        #pragma unroll
        for (int off = 32; off > 0; off >>= 1) {
            c_cnt[s] += __shfl_down(c_cnt[s], off, 64);
            c_r[s]   += __shfl_down(c_r[s],   off, 64);
            c_g[s]   += __shfl_down(c_g[s],   off, 64);
            c_b[s]   += __shfl_down(c_b[s],   off, 64);
        }
    }
    int wid = threadIdx.x >> 6;
    if ((threadIdx.x & 63) == 0) {
        #pragma unroll
        for (int s = 0; s < NSEG; ++s) {
            s_red[wid][s]      = c_cnt[s];
            s_red[wid][10 + s] = c_r[s];
            s_red[wid][20 + s] = c_g[s];
            s_red[wid][30 + s] = c_b[s];
        }
    }
    __syncthreads();
    uint32_t* slice = wsu + WS_SLICE + (size_t)blockIdx.x * SLICE_W;
    for (int j = threadIdx.x; j < HIST_WORDS; j += 256) slice[j] = s_hist[j];
    if (threadIdx.x < 40) {
        float v = s_red[0][threadIdx.x] + s_red[1][threadIdx.x]
                + s_red[2][threadIdx.x] + s_red[3][threadIdx.x];
        ((float*)slice)[HIST_WORDS + threadIdx.x] = v;
    }
}

// k3a: reduce 1024 slices -> NPART partials (plain stores, no atomics/init)
__global__ __launch_bounds__(256) void k3a_reduce(uint32_t* __restrict__ wsu) {
    int j = blockIdx.x * 256 + threadIdx.x;
    if (j >= SLICE_W) return;
    int y = blockIdx.y;
    const uint32_t* p = wsu + WS_SLICE + (size_t)(y * (K2_BLOCKS/NPART)) * SLICE_W + j;
    if (j < HIST_WORDS) {
        uint32_t acc = 0;
        #pragma unroll 4
        for (int b = 0; b < K2_BLOCKS/NPART; ++b) acc += p[(size_t)b * SLICE_W];
        wsu[WS_PART + y*SLICE_W + j] = acc;
    } else {
        float acc = 0.0f;
        #pragma unroll 4
        for (int b = 0; b < K2_BLOCKS/NPART; ++b) acc += ((const float*)p)[(size_t)b * SLICE_W];
        ((float*)wsu)[WS_PART + y*SLICE_W + j] = acc;
    }
}

// k3b: final partial sum + bottom-k scan + D_seg + dmin/dmax publish (1 block)
__global__ void k3b_stats(uint32_t* __restrict__ wsu) {
    __shared__ uint32_t s_hist[HIST_WORDS];
    __shared__ float s_acc[40];
    __shared__ float smn[4], smx[4];
    float* wsf = (float*)wsu;
    for (int j = threadIdx.x; j < SLICE_W; j += 256) {
        if (j < HIST_WORDS) {
            uint32_t acc = 0;
            #pragma unroll
            for (int y = 0; y < NPART; ++y) acc += wsu[WS_PART + y*SLICE_W + j];
            s_hist[j] = acc;
        } else {
            float acc = 0.0f;
            #pragma unroll
            for (int y = 0; y < NPART; ++y) acc += wsf[WS_PART + y*SLICE_W + j];
            s_acc[j - HIST_WORDS] = acc;
        }
    }
    float dmin, dmax;
    block_minmax(wsf, dmin, dmax, smn, smx);   // syncthreads inside covers s_hist/s_acc
    int s = threadIdx.x;
    if (s < NSEG) {
        float fn = s_acc[s];                   // exact integer-valued float
        uint32_t n = (uint32_t)(fn + 0.5f);
        uint32_t k = n / 100;                  // n * BOTTOM_PCT // 100
        const uint32_t* h = &s_hist[s*NB];
        float bsum = 0.0f; uint32_t taken = 0;
        for (int b = 0; b < NB; ++b) {
            uint32_t rem = k - taken;
            uint32_t c = h[b];
            uint32_t t = c < rem ? c : rem;
            bsum += (float)t * (((float)b + 0.5f) * BINW);
            taken += t;
        }
        if (taken < k) bsum += (float)(k - taken) * LOWR;
        float B = (k > 0) ? (bsum / (float)k) : 0.0f;
        wsf[WS_DSEG + s*4 + 0] = s_acc[10 + s] / fn - B;
        wsf[WS_DSEG + s*4 + 1] = s_acc[20 + s] / fn - B;
        wsf[WS_DSEG + s*4 + 2] = s_acc[30 + s] / fn - B;
        wsf[WS_DSEG + s*4 + 3] = 0.0f;
    } else if (s == NSEG) {
        wsf[WS_DSEG + 40] = 0.0f; wsf[WS_DSEG + 41] = 0.0f;
        wsf[WS_DSEG + 42] = 0.0f; wsf[WS_DSEG + 43] = 0.0f;
    } else if (s == NSEG+1) {
        wsf[WS_DMM] = dmin; wsf[WS_DMM + 1] = dmax;
    }
}

// k4: 3x3 depth-guided smoothing; reads staged dval (image never touched)
__global__ __launch_bounds__(256, 2) void k4_out(const float* __restrict__ depth,
                                                 const uint32_t* __restrict__ wsu,
                                                 float* __restrict__ out) {
    __shared__ float4 s_D4[NSEG+1];
    const float* wsf = (const float*)wsu;
    if (threadIdx.x < NSEG+1)
        s_D4[threadIdx.x] = ((const float4*)(wsf + WS_DSEG))[threadIdx.x];
    __syncthreads();

    float dmin = wsf[WS_DMM];
    float dmax = wsf[WS_DMM + 1];
    float invw = 10.0f / (dmax - dmin);

    int gid = blockIdx.x * 256 + threadIdx.x;       // one 4-px quad per thread
    int row = gid >> 9;                              // uniform per wave
    int col = (gid & 511) << 2;
    int lane = threadIdx.x & 63;

    float4 dva4 = ((const float4*)(wsf + WS_DVAL))[gid];

    float nd[3][6];
    #pragma unroll
    for (int rr = 0; rr < 3; ++rr) {
        int r2 = row + rr - 1;
        if (r2 >= 0 && r2 < HH) {                    // wave-uniform branch
            const float* dp = depth + (size_t)r2 * WW + col;
            float4 m = *(const float4*)dp;
            float left  = __shfl_up(m.w, 1, 64);
            float right = __shfl_down(m.x, 1, 64);
            if (lane == 0)  left  = (col > 0)      ? dp[-1] : INFINITY;
            if (lane == 63) right = (col + 4 < WW) ? dp[4]  : INFINITY;
            nd[rr][0] = left;  nd[rr][1] = m.x; nd[rr][2] = m.y;
            nd[rr][3] = m.z;   nd[rr][4] = m.w; nd[rr][5] = right;
        } else {
            #pragma unroll
            for (int cc = 0; cc < 6; ++cc) nd[rr][cc] = INFINITY;
        }
    }

    float cnt[4], A0[4], A1[4], A2[4];
    #pragma unroll
    for (int j = 0; j < 4; ++j) { cnt[j]=0.f; A0[j]=0.f; A1[j]=0.f; A2[j]=0.f; }

    #pragma unroll
    for (int rr = 0; rr < 3; ++rr) {
        #pragma unroll
        for (int cc = 0; cc < 6; ++cc) {
            float nv = nd[rr][cc];
            float4 dd = s_D4[seg_of(nv, dmin, dmax, invw)];
            #pragma unroll
            for (int j = 0; j < 4; ++j) {
                if (j >= cc - 2 && j <= cc) {        // compile-time folded
                    float msk = (fabsf(nv - nd[1][j+1]) < 1.0f) ? 1.0f : 0.0f;
                    cnt[j] += msk; A0[j] += msk*dd.x; A1[j] += msk*dd.y; A2[j] += msk*dd.z;
                }
            }
        }
    }

    float dva[4] = {dva4.x, dva4.y, dva4.z, dva4.w};
    float o0[4], o1[4], o2[4];
    #pragma unroll
    for (int j = 0; j < 4; ++j) {
        float rc = 1.0f / cnt[j];
        float4 Dc = s_D4[seg_of(nd[1][j+1], dmin, dmax, invw)];
        // E = F_SCALE*(P_MIX*D + (1-P_MIX)*a') = D + a'; J = E*d
        o0[j] = (Dc.x + A0[j]*rc) * dva[j];
        o1[j] = (Dc.y + A1[j]*rc) * dva[j];
        o2[j] = (Dc.z + A2[j]*rc) * dva[j];
    }
    size_t base = (size_t)row * WW + col;
    vfloat4 v0 = {o0[0], o0[1], o0[2], o0[3]};
    vfloat4 v1 = {o1[0], o1[1], o1[2], o1[3]};
    vfloat4 v2 = {o2[0], o2[1], o2[2], o2[3]};
    __builtin_nontemporal_store(v0, (vfloat4*)(out + base));
    __builtin_nontemporal_store(v1, (vfloat4*)(out + HWPX + base));
    __builtin_nontemporal_store(v2, (vfloat4*)(out + 2*HWPX + base));
}

extern "C" void kernel_launch(void* const* d_in, const int* in_sizes, int n_in,
                              void* d_out, int out_size, void* d_ws, size_t ws_size,
                              hipStream_t stream) {
    const float* image = (const float*)d_in[0];
    const float* depth = (const float*)d_in[1];
    const float* mu0   = (const float*)d_in[2];
    const float* mu1   = (const float*)d_in[3];
    const float* mu2   = (const float*)d_in[4];
    uint32_t* wsu = (uint32_t*)d_ws;
    float* out = (float*)d_out;

    hipLaunchKernelGGL(k1_minmax,  dim3(256),       dim3(256), 0, stream, depth, (float*)wsu);
    hipLaunchKernelGGL(k2_hist,    dim3(K2_BLOCKS), dim3(256), 0, stream,
                       image, depth, mu0, mu1, mu2, wsu);
    hipLaunchKernelGGL(k3a_reduce, dim3(6, NPART),  dim3(256), 0, stream, wsu);
    hipLaunchKernelGGL(k3b_stats,  dim3(1),         dim3(256), 0, stream, wsu);
    hipLaunchKernelGGL(k4_out,     dim3((HWPX/4)/256), dim3(256), 0, stream,
                       depth, wsu, out);
}

// Round 9
// 152.476 us; speedup vs baseline: 1.5723x; 1.0410x over previous
//
#include <hip/hip_runtime.h>
#include <cstdint>
#include <math.h>

#define HH 2048
#define WW 2048
#define HWPX (HH*WW)
#define NSEG 10
#define NB 128
#define HIST_WORDS (NSEG*NB)       // 1280
#define LOWR 0.03125f
#define INV_LOWW 4096.0f           // NB / LOWR
#define BINW (LOWR/(float)NB)      // 2.441e-4

#define K1_BLOCKS 512
#define K2_BLOCKS 512              // 2 blocks/CU exactly; halves slice traffic vs 1024
#define SLICE_W 1320               // 1280 hist + 40 acc per block
#define NPART 16                   // k3a reduction fan-in stage (512/16 = 32 slices each)

typedef float vfloat4 __attribute__((ext_vector_type(4)));

// workspace layout (32-bit words) — no init kernel: everything is written with
// plain stores before it is read (harness 0xAA poison is harmless).
#define WS_BMM 0                            // 1024: k1 per-block min[512], max[512]
#define WS_PART 1024                        // NPART * SLICE_W = 21120 partials
#define WS_DSEG 22144                       // 16B-aligned: 11 float4 (seg 10 = zeros)
#define WS_DMM (WS_DSEG + 44)               // dmin, dmax (published by k3b for k4)
#define WS_DVAL 22192                       // HWPX floats: dval staged k2 -> k4 (16.8 MB)
#define WS_SLICE (WS_DVAL + HWPX)           // K2_BLOCKS * SLICE_W (2.7 MB)

// Segment rule: replicates bins = linspace(dmin,dmax,11); pixel in seg s iff
// bins[s] <= v < bins[s+1]. v == dmax (== bins[10]) is in NO segment -> 10.
__device__ __forceinline__ int seg_of(float v, float dmin, float dmax, float invw) {
    int sg = (int)((v - dmin) * invw);
    sg = sg > (NSEG-1) ? (NSEG-1) : sg;
    return (v >= dmax) ? NSEG : sg;
}

// k1: per-block depth min/max -> plain stores (no atomics, no init required)
__global__ __launch_bounds__(256) void k1_minmax(const float* __restrict__ depth,
                                                 float* __restrict__ wsf) {
    int tid = blockIdx.x * 256 + threadIdx.x;
    int nth = K1_BLOCKS * 256;
    float vmin = INFINITY, vmax = 0.0f;
    const float4* d4 = (const float4*)depth;
    for (int i = tid; i < HWPX/4; i += nth) {
        float4 v = d4[i];
        vmin = fminf(vmin, fminf(fminf(v.x, v.y), fminf(v.z, v.w)));
        vmax = fmaxf(vmax, fmaxf(fmaxf(v.x, v.y), fmaxf(v.z, v.w)));
    }
    #pragma unroll
    for (int off = 32; off > 0; off >>= 1) {
        vmin = fminf(vmin, __shfl_down(vmin, off, 64));
        vmax = fmaxf(vmax, __shfl_down(vmax, off, 64));
    }
    __shared__ float smin[4], smax[4];
    int wid = threadIdx.x >> 6;
    if ((threadIdx.x & 63) == 0) { smin[wid] = vmin; smax[wid] = vmax; }
    __syncthreads();
    if (threadIdx.x == 0) {
        wsf[WS_BMM + blockIdx.x]             = fminf(fminf(smin[0], smin[1]), fminf(smin[2], smin[3]));
        wsf[WS_BMM + K1_BLOCKS + blockIdx.x] = fmaxf(fmaxf(smax[0], smax[1]), fmaxf(smax[2], smax[3]));
    }
}

// Each block re-reduces k1's 512+512 per-block values (4 KB, L2-hot).
__device__ __forceinline__ void block_minmax(const float* wsf, float& dmin, float& dmax,
                                             float smn[4], float smx[4]) {
    float v0 = fminf(wsf[WS_BMM + threadIdx.x], wsf[WS_BMM + 256 + threadIdx.x]);
    float v1 = fmaxf(wsf[WS_BMM + K1_BLOCKS + threadIdx.x],
                     wsf[WS_BMM + K1_BLOCKS + 256 + threadIdx.x]);
    #pragma unroll
    for (int off = 32; off > 0; off >>= 1) {
        v0 = fminf(v0, __shfl_down(v0, off, 64));
        v1 = fmaxf(v1, __shfl_down(v1, off, 64));
    }
    int wid = threadIdx.x >> 6;
    if ((threadIdx.x & 63) == 0) { smn[wid] = v0; smx[wid] = v1; }
    __syncthreads();
    dmin = fminf(fminf(smn[0], smn[1]), fminf(smn[2], smn[3]));
    dmax = fmaxf(fmaxf(smx[0], smx[1]), fmaxf(smx[2], smx[3]));
}

// k2: register per-seg stats; LDS hist only for m < LOWR (~9%); dval staged to
// ws for k4. Flush: nontemporal stores to private slice (read-once by k3a).
__global__ __launch_bounds__(256, 2) void k2_hist(const float* __restrict__ image,
                                                  const float* __restrict__ depth,
                                                  const float* __restrict__ mu0p,
                                                  const float* __restrict__ mu1p,
                                                  const float* __restrict__ mu2p,
                                                  uint32_t* __restrict__ wsu) {
    __shared__ uint32_t s_hist[HIST_WORDS];
    __shared__ float s_red[4][40];
    __shared__ float smn[4], smx[4];
    float* wsf = (float*)wsu;
    for (int j = threadIdx.x; j < HIST_WORDS; j += 256) s_hist[j] = 0;

    float dmin, dmax;
    block_minmax(wsf, dmin, dmax, smn, smx);       // includes the needed __syncthreads
    float invw = 10.0f / (dmax - dmin);
    float mu0 = *mu0p, mu1 = *mu1p, mu2 = *mu2p;

    float c_cnt[NSEG], c_r[NSEG], c_g[NSEG], c_b[NSEG];
    #pragma unroll
    for (int s = 0; s < NSEG; ++s) { c_cnt[s]=0.f; c_r[s]=0.f; c_g[s]=0.f; c_b[s]=0.f; }

    const float4* r4 = (const float4*)image;
    const float4* g4 = (const float4*)(image + HWPX);
    const float4* b4 = (const float4*)(image + 2*HWPX);
    const float4* d4 = (const float4*)depth;
    vfloat4* dval4 = (vfloat4*)(wsf + WS_DVAL);
    int tid = blockIdx.x * 256 + threadIdx.x;
    int nth = K2_BLOCKS * 256;
    for (int i = tid; i < HWPX/4; i += nth) {
        float4 rv = r4[i], gv = g4[i], bv = b4[i], dv = d4[i];
        float ra[4] = {rv.x, rv.y, rv.z, rv.w};
        float ga[4] = {gv.x, gv.y, gv.z, gv.w};
        float ba[4] = {bv.x, bv.y, bv.z, bv.w};
        float da[4] = {dv.x, dv.y, dv.z, dv.w};
        float dvo[4];
        #pragma unroll
        for (int j = 0; j < 4; ++j) {
            int sg = seg_of(da[j], dmin, dmax, invw);
            float m = fminf(ra[j], fminf(ga[j], ba[j]));
            if (sg < NSEG && m < LOWR) {
                atomicAdd(&s_hist[sg*NB + (int)(m * INV_LOWW)], 1u);
            }
            #pragma unroll
            for (int s = 0; s < NSEG; ++s) {
                float sel = (sg == s) ? 1.0f : 0.0f;
                c_cnt[s] += sel;
                c_r[s] += sel * ra[j];
                c_g[s] += sel * ga[j];
                c_b[s] += sel * ba[j];
            }
            dvo[j] = mu0 + mu1 * fmaxf(ga[j], ba[j]) + mu2 * ra[j];
        }
        vfloat4 dq = {dvo[0], dvo[1], dvo[2], dvo[3]};
        dval4[i] = dq;
    }
    #pragma unroll
    for (int s = 0; s < NSEG; ++s) {
        #pragma unroll
        for (int off = 32; off > 0; off >>= 1) {
            c_cnt[s] += __shfl_down(c_cnt[s], off, 64);
            c_r[s]   += __shfl_down(c_r[s],   off, 64);
            c_g[s]   += __shfl_down(c_g[s],   off, 64);
            c_b[s]   += __shfl_down(c_b[s],   off, 64);
        }
    }
    int wid = threadIdx.x >> 6;
    if ((threadIdx.x & 63) == 0) {
        #pragma unroll
        for (int s = 0; s < NSEG; ++s) {
            s_red[wid][s]      = c_cnt[s];
            s_red[wid][10 + s] = c_r[s];
            s_red[wid][20 + s] = c_g[s];
            s_red[wid][30 + s] = c_b[s];
        }
    }
    __syncthreads();
    uint32_t* slice = wsu + WS_SLICE + (size_t)blockIdx.x * SLICE_W;
    for (int j = threadIdx.x; j < HIST_WORDS; j += 256)
        __builtin_nontemporal_store(s_hist[j], &slice[j]);
    if (threadIdx.x < 40) {
        float v = s_red[0][threadIdx.x] + s_red[1][threadIdx.x]
                + s_red[2][threadIdx.x] + s_red[3][threadIdx.x];
        __builtin_nontemporal_store(v, &((float*)slice)[HIST_WORDS + threadIdx.x]);
    }
}

// k3a: reduce K2_BLOCKS slices -> NPART partials (plain stores, no atomics/init)
__global__ __launch_bounds__(256) void k3a_reduce(uint32_t* __restrict__ wsu) {
    int j = blockIdx.x * 256 + threadIdx.x;
    if (j >= SLICE_W) return;
    int y = blockIdx.y;
    const uint32_t* p = wsu + WS_SLICE + (size_t)(y * (K2_BLOCKS/NPART)) * SLICE_W + j;
    if (j < HIST_WORDS) {
        uint32_t acc = 0;
        #pragma unroll 4
        for (int b = 0; b < K2_BLOCKS/NPART; ++b) acc += p[(size_t)b * SLICE_W];
        wsu[WS_PART + y*SLICE_W + j] = acc;
    } else {
        float acc = 0.0f;
        #pragma unroll 4
        for (int b = 0; b < K2_BLOCKS/NPART; ++b) acc += ((const float*)p)[(size_t)b * SLICE_W];
        ((float*)wsu)[WS_PART + y*SLICE_W + j] = acc;
    }
}

// k3b: final partial sum + bottom-k scan + D_seg + dmin/dmax publish (1 block)
__global__ void k3b_stats(uint32_t* __restrict__ wsu) {
    __shared__ uint32_t s_hist[HIST_WORDS];
    __shared__ float s_acc[40];
    __shared__ float smn[4], smx[4];
    float* wsf = (float*)wsu;
    for (int j = threadIdx.x; j < SLICE_W; j += 256) {
        if (j < HIST_WORDS) {
            uint32_t acc = 0;
            #pragma unroll
            for (int y = 0; y < NPART; ++y) acc += wsu[WS_PART + y*SLICE_W + j];
            s_hist[j] = acc;
        } else {
            float acc = 0.0f;
            #pragma unroll
            for (int y = 0; y < NPART; ++y) acc += wsf[WS_PART + y*SLICE_W + j];
            s_acc[j - HIST_WORDS] = acc;
        }
    }
    float dmin, dmax;
    block_minmax(wsf, dmin, dmax, smn, smx);   // syncthreads inside covers s_hist/s_acc
    int s = threadIdx.x;
    if (s < NSEG) {
        float fn = s_acc[s];                   // exact integer-valued float
        uint32_t n = (uint32_t)(fn + 0.5f);
        uint32_t k = n / 100;                  // n * BOTTOM_PCT // 100
        const uint32_t* h = &s_hist[s*NB];
        float bsum = 0.0f; uint32_t taken = 0;
        for (int b = 0; b < NB; ++b) {
            uint32_t rem = k - taken;
            uint32_t c = h[b];
            uint32_t t = c < rem ? c : rem;
            bsum += (float)t * (((float)b + 0.5f) * BINW);
            taken += t;
        }
        if (taken < k) bsum += (float)(k - taken) * LOWR;
        float B = (k > 0) ? (bsum / (float)k) : 0.0f;
        wsf[WS_DSEG + s*4 + 0] = s_acc[10 + s] / fn - B;
        wsf[WS_DSEG + s*4 + 1] = s_acc[20 + s] / fn - B;
        wsf[WS_DSEG + s*4 + 2] = s_acc[30 + s] / fn - B;
        wsf[WS_DSEG + s*4 + 3] = 0.0f;
    } else if (s == NSEG) {
        wsf[WS_DSEG + 40] = 0.0f; wsf[WS_DSEG + 41] = 0.0f;
        wsf[WS_DSEG + 42] = 0.0f; wsf[WS_DSEG + 43] = 0.0f;
    } else if (s == NSEG+1) {
        wsf[WS_DMM] = dmin; wsf[WS_DMM + 1] = dmax;
    }
}

// k4: 3x3 depth-guided smoothing; reads staged dval (image never touched)
__global__ __launch_bounds__(256, 2) void k4_out(const float* __restrict__ depth,
                                                 const uint32_t* __restrict__ wsu,
                                                 float* __restrict__ out) {
    __shared__ float4 s_D4[NSEG+1];
    const float* wsf = (const float*)wsu;
    if (threadIdx.x < NSEG+1)
        s_D4[threadIdx.x] = ((const float4*)(wsf + WS_DSEG))[threadIdx.x];
    __syncthreads();

    float dmin = wsf[WS_DMM];
    float dmax = wsf[WS_DMM + 1];
    float invw = 10.0f / (dmax - dmin);

    int gid = blockIdx.x * 256 + threadIdx.x;       // one 4-px quad per thread
    int row = gid >> 9;                              // uniform per wave
    int col = (gid & 511) << 2;
    int lane = threadIdx.x & 63;

    float4 dva4 = ((const float4*)(wsf + WS_DVAL))[gid];

    float nd[3][6];
    #pragma unroll
    for (int rr = 0; rr < 3; ++rr) {
        int r2 = row + rr - 1;
        if (r2 >= 0 && r2 < HH) {                    // wave-uniform branch
            const float* dp = depth + (size_t)r2 * WW + col;
            float4 m = *(const float4*)dp;
            float left  = __shfl_up(m.w, 1, 64);
            float right = __shfl_down(m.x, 1, 64);
            if (lane == 0)  left  = (col > 0)      ? dp[-1] : INFINITY;
            if (lane == 63) right = (col + 4 < WW) ? dp[4]  : INFINITY;
            nd[rr][0] = left;  nd[rr][1] = m.x; nd[rr][2] = m.y;
            nd[rr][3] = m.z;   nd[rr][4] = m.w; nd[rr][5] = right;
        } else {
            #pragma unroll
            for (int cc = 0; cc < 6; ++cc) nd[rr][cc] = INFINITY;
        }
    }

    float cnt[4], A0[4], A1[4], A2[4];
    #pragma unroll
    for (int j = 0; j < 4; ++j) { cnt[j]=0.f; A0[j]=0.f; A1[j]=0.f; A2[j]=0.f; }

    #pragma unroll
    for (int rr = 0; rr < 3; ++rr) {
        #pragma unroll
        for (int cc = 0; cc < 6; ++cc) {
            float nv = nd[rr][cc];
            float4 dd = s_D4[seg_of(nv, dmin, dmax, invw)];
            #pragma unroll
            for (int j = 0; j < 4; ++j) {
                if (j >= cc - 2 && j <= cc) {        // compile-time folded
                    float msk = (fabsf(nv - nd[1][j+1]) < 1.0f) ? 1.0f : 0.0f;
                    cnt[j] += msk; A0[j] += msk*dd.x; A1[j] += msk*dd.y; A2[j] += msk*dd.z;
                }
            }
        }
    }

    float dva[4] = {dva4.x, dva4.y, dva4.z, dva4.w};
    float o0[4], o1[4], o2[4];
    #pragma unroll
    for (int j = 0; j < 4; ++j) {
        float rc = 1.0f / cnt[j];
        float4 Dc = s_D4[seg_of(nd[1][j+1], dmin, dmax, invw)];
        // E = F_SCALE*(P_MIX*D + (1-P_MIX)*a') = D + a'; J = E*d
        o0[j] = (Dc.x + A0[j]*rc) * dva[j];
        o1[j] = (Dc.y + A1[j]*rc) * dva[j];
        o2[j] = (Dc.z + A2[j]*rc) * dva[j];
    }
    size_t base = (size_t)row * WW + col;
    vfloat4 v0 = {o0[0], o0[1], o0[2], o0[3]};
    vfloat4 v1 = {o1[0], o1[1], o1[2], o1[3]};
    vfloat4 v2 = {o2[0], o2[1], o2[2], o2[3]};
    __builtin_nontemporal_store(v0, (vfloat4*)(out + base));
    __builtin_nontemporal_store(v1, (vfloat4*)(out + HWPX + base));
    __builtin_nontemporal_store(v2, (vfloat4*)(out + 2*HWPX + base));
}

extern "C" void kernel_launch(void* const* d_in, const int* in_sizes, int n_in,
                              void* d_out, int out_size, void* d_ws, size_t ws_size,
                              hipStream_t stream) {
    const float* image = (const float*)d_in[0];
    const float* depth = (const float*)d_in[1];
    const float* mu0   = (const float*)d_in[2];
    const float* mu1   = (const float*)d_in[3];
    const float* mu2   = (const float*)d_in[4];
    uint32_t* wsu = (uint32_t*)d_ws;
    float* out = (float*)d_out;

    hipLaunchKernelGGL(k1_minmax,  dim3(K1_BLOCKS), dim3(256), 0, stream, depth, (float*)wsu);
    hipLaunchKernelGGL(k2_hist,    dim3(K2_BLOCKS), dim3(256), 0, stream,
                       image, depth, mu0, mu1, mu2, wsu);
    hipLaunchKernelGGL(k3a_reduce, dim3(6, NPART),  dim3(256), 0, stream, wsu);
    hipLaunchKernelGGL(k3b_stats,  dim3(1),         dim3(256), 0, stream, wsu);
    hipLaunchKernelGGL(k4_out,     dim3((HWPX/4)/256), dim3(256), 0, stream,
                       depth, wsu, out);
}